// Round 1
// baseline (514.497 us; speedup 1.0000x reference)
//
#include <hip/hip_runtime.h>
#include <cstdint>

#define B_SZ 8192
#define D_SZ 1024
#define E_SZ 16
#define H_SZ 1024

using short8 = __attribute__((ext_vector_type(8))) short;
using f32x4  = __attribute__((ext_vector_type(4))) float;

__device__ __forceinline__ unsigned short f2bf(float f) {
  union { float f; unsigned int u; } v; v.f = f;
  unsigned int u = v.u;
  return (unsigned short)((u + 0x7fffu + ((u >> 16) & 1u)) >> 16);  // RNE
}

__device__ __forceinline__ void async_ld16(void* lds, const void* g) {
  __builtin_amdgcn_global_load_lds(
      reinterpret_cast<const unsigned int __attribute__((address_space(1)))*>(
          reinterpret_cast<uintptr_t>(g)),
      reinterpret_cast<unsigned int __attribute__((address_space(3)))*>(
          reinterpret_cast<uintptr_t>(lds)),
      16, 0, 0);
}

// ---------------- x -> bf16, zero accumulators ----------------
__global__ __launch_bounds__(256) void xcast(const float* __restrict__ x,
                                             unsigned short* __restrict__ xb,
                                             float* __restrict__ accum) {
  const size_t i = (size_t)blockIdx.x * 256 + threadIdx.x;  // float4 index
  float4 v = ((const float4*)x)[i];
  unsigned long long r = (unsigned long long)f2bf(v.x)
      | ((unsigned long long)f2bf(v.y) << 16)
      | ((unsigned long long)f2bf(v.z) << 32)
      | ((unsigned long long)f2bf(v.w) << 48);
  ((unsigned long long*)xb)[i] = r;
  if (blockIdx.x == 0 && threadIdx.x < 32) accum[threadIdx.x] = 0.0f;
}

// ---------------- expert_w (E,D,H) fp32 -> Wt (E,H,D) bf16 ----------------
__global__ __launch_bounds__(256) void wtconv(const float* __restrict__ W,
                                              unsigned short* __restrict__ Wt) {
  __shared__ float t[64][65];
  const int e  = blockIdx.z;
  const int d0 = blockIdx.x * 64;
  const int h0 = blockIdx.y * 64;
  const float* We = W + (size_t)e * D_SZ * H_SZ;
  unsigned short* Wte = Wt + (size_t)e * D_SZ * H_SZ;
  #pragma unroll
  for (int i = 0; i < 16; ++i) {
    const int idx = i * 256 + threadIdx.x;
    const int r = idx >> 6, c = idx & 63;
    t[r][c] = We[(size_t)(d0 + r) * H_SZ + h0 + c];
  }
  __syncthreads();
  #pragma unroll
  for (int i = 0; i < 16; ++i) {
    const int idx = i * 256 + threadIdx.x;
    const int r = idx >> 6, c = idx & 63;   // r = h within tile, c = d within tile
    Wte[(size_t)(h0 + r) * D_SZ + d0 + c] = f2bf(t[c][r]);
  }
}

// ---------------- clean / raw-noise logits (fp32) ----------------
__global__ __launch_bounds__(256) void gating_logits(
    const float* __restrict__ x, const float* __restrict__ wg,
    const float* __restrict__ wn, float* __restrict__ cl, float* __restrict__ rn) {
  __shared__ __align__(16) float sx[16][1024];
  const int tid = threadIdx.x;
  const size_t rowbase = (size_t)blockIdx.x * 16;
  const float4* xs = (const float4*)(x + rowbase * D_SZ);
  float4* sx4 = (float4*)&sx[0][0];
  #pragma unroll
  for (int i = 0; i < 16; ++i) sx4[i * 256 + tid] = xs[i * 256 + tid];
  __syncthreads();
  #pragma unroll
  for (int h = 0; h < 2; ++h) {
    const int id = h * 256 + tid;
    const int r = id >> 5;
    const int c = id & 31;
    const float* w = (c < 16) ? (wg + c) : (wn + (c - 16));
    float s = 0.0f;
    #pragma unroll 8
    for (int d = 0; d < 1024; ++d) s = fmaf(sx[r][d], w[(size_t)d * 16], s);
    if (c < 16) cl[(rowbase + r) * 16 + c] = s;
    else        rn[(rowbase + r) * 16 + (c - 16)] = s;
  }
}

// ---------------- per-row gating: softmax, top-9, gates, load/importance ----------------
__global__ __launch_bounds__(256) void gating_post(
    const float* __restrict__ clg, const float* __restrict__ rng,
    const float* __restrict__ noise, float* __restrict__ gates,
    float* __restrict__ accum) {
  const int row = blockIdx.x * 256 + threadIdx.x;
  float cl[16], sd[16], nl[16], p[16];
  #pragma unroll
  for (int e = 0; e < 16; ++e) {
    cl[e] = clg[(size_t)row * 16 + e];
    const float r = rng[(size_t)row * 16 + e];
    sd[e] = fmaxf(r, 0.0f) + log1pf(expf(-fabsf(r))) + 0.01f;  // softplus + eps
    nl[e] = cl[e] + noise[(size_t)row * 16 + e] * sd[e];
  }
  float mx = nl[0];
  #pragma unroll
  for (int e = 1; e < 16; ++e) mx = fmaxf(mx, nl[e]);
  float sum = 0.0f;
  #pragma unroll
  for (int e = 0; e < 16; ++e) { p[e] = expf(nl[e] - mx); sum += p[e]; }
  const float inv = 1.0f / sum;
  #pragma unroll
  for (int e = 0; e < 16; ++e) p[e] *= inv;
  // top-9 selection (ties -> lowest index, matches lax.top_k)
  float tmp[16];
  #pragma unroll
  for (int e = 0; e < 16; ++e) tmp[e] = p[e];
  float tv[9]; int ti[9];
  for (int k = 0; k < 9; ++k) {
    float bv = tmp[0]; int bj = 0;
    #pragma unroll
    for (int j = 1; j < 16; ++j) if (tmp[j] > bv) { bv = tmp[j]; bj = j; }
    tv[k] = bv; ti[k] = bj; tmp[bj] = -1.0f;
  }
  float s8 = 0.0f;
  #pragma unroll
  for (int k = 0; k < 8; ++k) s8 += tv[k];
  const float denom = s8 + 1e-6f;
  float g[16];
  #pragma unroll
  for (int e = 0; e < 16; ++e) g[e] = 0.0f;
  for (int k = 0; k < 8; ++k) g[ti[k]] = tv[k] / denom;
  const float thr_in = tv[8], thr_out = tv[7];
  float lc[16];
  #pragma unroll
  for (int e = 0; e < 16; ++e) {
    const float t = (nl[e] > thr_in) ? thr_in : thr_out;
    lc[e] = 0.5f * (1.0f + erff(((cl[e] - t) / sd[e]) * 0.70710678118654752f));
  }
  #pragma unroll
  for (int e = 0; e < 16; ++e) gates[(size_t)row * 16 + e] = g[e];
  // wave-reduce then one atomic per wave
  #pragma unroll
  for (int e = 0; e < 16; ++e) {
    float vi = g[e], vl = lc[e];
    for (int o = 32; o > 0; o >>= 1) { vi += __shfl_down(vi, o); vl += __shfl_down(vl, o); }
    if ((threadIdx.x & 63) == 0) {
      atomicAdd(&accum[e], vi);
      atomicAdd(&accum[16 + e], vl);
    }
  }
}

// ---------------- fused MoE GEMM: y = sum_e g[:,e] * (Xb @ We^T) + g @ eb ----------------
__global__ __launch_bounds__(256, 2) void moe_gemm(
    const unsigned short* __restrict__ Xb,   // [B][D] bf16
    const unsigned short* __restrict__ Wt,   // [E][H][D] bf16
    const float* __restrict__ gates,         // [B][E]
    const float* __restrict__ ebias,         // [E][H]
    float* __restrict__ y) {                 // [B][H]
  __shared__ __align__(16) unsigned short sA[128 * 64];  // [m][k-chunk swizzled]
  __shared__ __align__(16) unsigned short sB[128 * 64];  // [n][k-chunk swizzled]
  __shared__ __align__(16) float sG[128 * 16];
  __shared__ __align__(16) float sEB[16 * 128];

  const int tid  = threadIdx.x;
  const int lane = tid & 63;
  const int wave = tid >> 6;
  const int wm = wave >> 1, wn = wave & 1;
  const int ml = lane & 15;
  const int quad = lane >> 4;
  const int row0 = blockIdx.x * 128;
  const int col0 = blockIdx.y * 128;
  const int wbase = tid & ~63;

  {  // stage gates tile (128x16) and bias tile (16x128)
    const int m = tid >> 1, off = (tid & 1) * 8;
    const float4* s1 = (const float4*)(gates + (size_t)(row0 + m) * 16 + off);
    float4* dG = (float4*)(sG + m * 16 + off);
    dG[0] = s1[0]; dG[1] = s1[1];
    const int e = tid >> 4, c = (tid & 15) * 8;
    const float4* s2 = (const float4*)(ebias + (size_t)e * H_SZ + col0 + c);
    float4* dE = (float4*)(sEB + e * 128 + c);
    dE[0] = s2[0]; dE[1] = s2[1];
  }

  f32x4 acc2[4][4] = {};

  for (int e = 0; e < 16; ++e) {
    const unsigned short* We = Wt + (size_t)e * D_SZ * H_SZ;
    f32x4 acc[4][4] = {};
    for (int kb = 0; kb < 16; ++kb) {
      const int k0 = kb * 64;
      __syncthreads();  // previous iter's LDS reads done
      #pragma unroll
      for (int i = 0; i < 4; ++i) {  // A tile: 128x64 bf16, XOR-swizzled 16B chunks
        const int s = i * 256 + tid;
        const int m = s >> 3, pp = s & 7;
        const int gc = pp ^ (m & 7);
        async_ld16(sA + (size_t)(i * 256 + wbase) * 8,
                   Xb + (size_t)(row0 + m) * D_SZ + (size_t)(k0 + gc * 8));
      }
      #pragma unroll
      for (int i = 0; i < 4; ++i) {  // B tile: 128x64 bf16 (n-major), swizzled
        const int s = i * 256 + tid;
        const int n = s >> 3, pp = s & 7;
        const int gc = pp ^ (n & 7);
        async_ld16(sB + (size_t)(i * 256 + wbase) * 8,
                   We + (size_t)(col0 + n) * D_SZ + (size_t)(k0 + gc * 8));
      }
      __syncthreads();  // staging visible
      #pragma unroll
      for (int kk = 0; kk < 2; ++kk) {
        short8 af[4], bfr[4];
        #pragma unroll
        for (int i = 0; i < 4; ++i) {
          const int m = wm * 64 + i * 16 + ml;
          const int cA = kk * 4 + quad;
          af[i]  = *(const short8*)(sA + ((size_t)m * 8 + (cA ^ (m & 7))) * 8);
          const int n = wn * 64 + i * 16 + ml;
          bfr[i] = *(const short8*)(sB + ((size_t)n * 8 + (cA ^ (n & 7))) * 8);
        }
        #pragma unroll
        for (int i = 0; i < 4; ++i)
          #pragma unroll
          for (int j = 0; j < 4; ++j)
            acc[i][j] = __builtin_amdgcn_mfma_f32_16x16x32_bf16(af[i], bfr[j], acc[i][j], 0, 0, 0);
      }
    }
    // per-expert epilogue: acc2 += g[row,e] * acc   (C layout: col=lane&15, row=quad*4+r)
    #pragma unroll
    for (int i = 0; i < 4; ++i) {
      const int mrow = wm * 64 + i * 16 + quad * 4;
      #pragma unroll
      for (int r = 0; r < 4; ++r) {
        const float gv = sG[(mrow + r) * 16 + e];
        #pragma unroll
        for (int j = 0; j < 4; ++j) acc2[i][j][r] += gv * acc[i][j][r];
      }
    }
  }

  // final epilogue: bias (g row . eb col) + store
  #pragma unroll
  for (int i = 0; i < 4; ++i) {
    const int mrow = wm * 64 + i * 16 + quad * 4;
    #pragma unroll
    for (int r = 0; r < 4; ++r) {
      const int row = row0 + mrow + r;
      #pragma unroll
      for (int j = 0; j < 4; ++j) {
        const int cc = wn * 64 + j * 16 + ml;
        float bias = 0.0f;
        #pragma unroll
        for (int e2 = 0; e2 < 16; ++e2)
          bias += sG[(mrow + r) * 16 + e2] * sEB[e2 * 128 + cc];
        y[(size_t)row * H_SZ + col0 + cc] = acc2[i][j][r] + bias;
      }
    }
  }
}

// ---------------- loss finalize ----------------
__global__ void loss_k(const float* __restrict__ accum, float* __restrict__ out) {
  if (threadIdx.x == 0) {
    double si = 0.0, sl = 0.0;
    for (int e = 0; e < 16; ++e) { si += accum[e]; sl += accum[16 + e]; }
    const double mi = si / 16.0, mld = sl / 16.0;
    double vi = 0.0, vl = 0.0;
    for (int e = 0; e < 16; ++e) {
      const double di = accum[e] - mi;       vi += di * di;
      const double dl = accum[16 + e] - mld; vl += dl * dl;
    }
    vi /= 15.0; vl /= 15.0;  // ddof=1
    const double loss = 0.01 * (vi / (mi * mi + 1e-10) + vl / (mld * mld + 1e-10));
    out[(size_t)B_SZ * H_SZ] = (float)loss;
  }
}

extern "C" void kernel_launch(void* const* d_in, const int* in_sizes, int n_in,
                              void* d_out, int out_size, void* d_ws, size_t ws_size,
                              hipStream_t stream) {
  (void)in_sizes; (void)n_in; (void)out_size; (void)ws_size;
  const float* x  = (const float*)d_in[0];
  const float* wg = (const float*)d_in[1];
  const float* wnoi = (const float*)d_in[2];
  const float* ew = (const float*)d_in[3];
  const float* eb = (const float*)d_in[4];
  const float* nz = (const float*)d_in[5];
  float* y = (float*)d_out;

  char* ws = (char*)d_ws;
  unsigned short* xb  = (unsigned short*)(ws);                       // 16 MB
  unsigned short* wtb = (unsigned short*)(ws + (size_t)16777216);    // 32 MB
  float* cl    = (float*)(ws + (size_t)50331648);                    // 512 KB
  float* rn    = (float*)(ws + (size_t)50331648 + 524288);           // 512 KB
  float* gates = (float*)(ws + (size_t)50331648 + 1048576);          // 512 KB
  float* accum = (float*)(ws + (size_t)50331648 + 1572864);          // 128 B

  hipLaunchKernelGGL(xcast,         dim3(8192),       dim3(256), 0, stream, x, xb, accum);
  hipLaunchKernelGGL(wtconv,        dim3(16, 16, 16), dim3(256), 0, stream, ew, wtb);
  hipLaunchKernelGGL(gating_logits, dim3(512),        dim3(256), 0, stream, x, wg, wnoi, cl, rn);
  hipLaunchKernelGGL(gating_post,   dim3(32),         dim3(256), 0, stream, cl, rn, nz, gates, accum);
  hipLaunchKernelGGL(moe_gemm,      dim3(64, 8),      dim3(256), 0, stream, xb, wtb, gates, eb, y);
  hipLaunchKernelGGL(loss_k,        dim3(1),          dim3(64),  0, stream, accum, y);
}